// Round 7
// baseline (2104.563 us; speedup 1.0000x reference)
//
#include <hip/hip_runtime.h>
#include <math.h>

// Problem constants (reference: BS=32, N=M=1024, eps=0.1, 200 iters)
#define BS    32
#define N     1024
#define M     1024
#define ITERS 200

// Two batches per WG, 16 WGs per batch, 512 threads -> grid 256 = 1 WG/CU.
// Per WG per batch: 64 rows on-chip (32 rows in VGPRs, 32 rows in LDS).
// The exchange (barrier wait + L3 partial reads) of batch A is overlapped
// with the sweep of batch B and vice versa.
#define WPB   16                 // WGs per batch
#define T     512                // 8 waves
#define NW    8
#define RREG  4                  // register rows / wave / batch
#define RLDS  4                  // LDS rows / wave / batch
#define RPB   (NW * (RREG + RLDS))   // 64 rows per WG per batch

// ws: counters + double-buffered column partials [2][BS][WPB][M] (16 MB)
#define CNT_BYTES  4096
#define PART_OFF   ((size_t)CNT_BYTES)
#define PART_BYTES ((size_t)2 * BS * WPB * M * 4)
#define WS_NEEDED  (PART_OFF + PART_BYTES)

// unpack two u16 from a 32-bit word to floats (raw, unscaled)
__device__ __forceinline__ float2 upair(unsigned w) {
    return make_float2((float)(w & 0xffffu), (float)(w >> 16));
}

// Ghat = round(65535 * exp(-10*C)); the 1/65535 scales cancel algebraically:
//   u' = MU/(Ghat.v) == u/65535 ; col = sum u'*Ghat == u^T G ;
//   Gamma*n = u' * Ghat * v * N
__device__ __forceinline__ unsigned qq(float c0, float c1) {
    const float KE = -14.4269504088896340f;   // -10*log2(e)
    unsigned a = __float2uint_rn(65535.0f * __builtin_amdgcn_exp2f(KE * c0));
    unsigned b = __float2uint_rn(65535.0f * __builtin_amdgcn_exp2f(KE * c1));
    return a | (b << 16);
}

// ---- macros (textual expansion guarantees static VGPR-array indexing) ----

#define QUANT(SL, QA, QB, AB) do {                                            \
    _Pragma("unroll")                                                         \
    for (int i_ = 0; i_ < RREG; ++i_) {                                       \
        const float4* cr_ = (const float4*)(C + (SL) + (size_t)(wave*8+i_)*M);\
        float4 a0_=cr_[lane], a1_=cr_[64+lane];                               \
        float4 b0_=cr_[128+lane], b1_=cr_[192+lane];                          \
        QA[i_].x=qq(a0_.x,a0_.y); QA[i_].y=qq(a0_.z,a0_.w);                   \
        QA[i_].z=qq(a1_.x,a1_.y); QA[i_].w=qq(a1_.z,a1_.w);                   \
        QB[i_].x=qq(b0_.x,b0_.y); QB[i_].y=qq(b0_.z,b0_.w);                   \
        QB[i_].z=qq(b1_.x,b1_.y); QB[i_].w=qq(b1_.z,b1_.w);                   \
    }                                                                         \
    _Pragma("unroll")                                                         \
    for (int j_ = 0; j_ < RLDS; ++j_) {                                       \
        const float4* cr_ = (const float4*)(C + (SL) +                        \
                                            (size_t)(wave*8+RREG+j_)*M);      \
        float4 a0_=cr_[lane], a1_=cr_[64+lane];                               \
        float4 b0_=cr_[128+lane], b1_=cr_[192+lane];                          \
        uint4 oa_, ob_;                                                       \
        oa_.x=qq(a0_.x,a0_.y); oa_.y=qq(a0_.z,a0_.w);                         \
        oa_.z=qq(a1_.x,a1_.y); oa_.w=qq(a1_.z,a1_.w);                         \
        ob_.x=qq(b0_.x,b0_.y); ob_.y=qq(b0_.z,b0_.w);                         \
        ob_.z=qq(b1_.x,b1_.y); ob_.w=qq(b1_.z,b1_.w);                         \
        Glds[AB][wave*RLDS+j_][lane]    = oa_;                                \
        Glds[AB][wave*RLDS+j_][64+lane] = ob_;                                \
    }                                                                         \
} while (0)

#define DOROW(QAV, QBV, UIDX, AB) do {                                        \
    float2 g0_=upair((QAV).x), g1_=upair((QAV).y),                            \
           g2_=upair((QAV).z), g3_=upair((QAV).w);                            \
    float2 h0_=upair((QBV).x), h1_=upair((QBV).y),                            \
           h2_=upair((QBV).z), h3_=upair((QBV).w);                            \
    float pa_=(g0_.x*vra0.x+g0_.y*vra0.y)+(g1_.x*vra0.z+g1_.y*vra0.w);        \
    float pb_=(g2_.x*vra1.x+g2_.y*vra1.y)+(g3_.x*vra1.z+g3_.y*vra1.w);        \
    float pc_=(h0_.x*vrb0.x+h0_.y*vrb0.y)+(h1_.x*vrb0.z+h1_.y*vrb0.w);        \
    float pd_=(h2_.x*vrb1.x+h2_.y*vrb1.y)+(h3_.x*vrb1.z+h3_.y*vrb1.w);        \
    float dot_=(pa_+pb_)+(pc_+pd_);                                           \
    _Pragma("unroll")                                                         \
    for (int o_ = 32; o_ > 0; o_ >>= 1) dot_ += __shfl_xor(dot_, o_, 64);     \
    float ui_ = MU / dot_;                                                    \
    if (lane == 0) u_lds[AB][UIDX] = ui_;                                     \
    ca0.x+=ui_*g0_.x; ca0.y+=ui_*g0_.y; ca0.z+=ui_*g1_.x; ca0.w+=ui_*g1_.y;   \
    ca1.x+=ui_*g2_.x; ca1.y+=ui_*g2_.y; ca1.z+=ui_*g3_.x; ca1.w+=ui_*g3_.y;   \
    cb0.x+=ui_*h0_.x; cb0.y+=ui_*h0_.y; cb0.z+=ui_*h1_.x; cb0.w+=ui_*h1_.y;   \
    cb1.x+=ui_*h2_.x; cb1.y+=ui_*h2_.y; cb1.z+=ui_*h3_.x; cb1.w+=ui_*h3_.y;   \
} while (0)

#define ADD4_(d, s) do { d.x+=s.x; d.y+=s.y; d.z+=s.z; d.w+=s.w; } while (0)

// sweep own 64 rows of batch AB, combine 8 waves (2-stage in part4),
// write WG column-partial to global, arrive at the batch barrier.
#define SWEEPCOMB(QA, QB, AB, BATCH, PAR) do {                                \
    const float4* v4_ = (const float4*)v_lds[AB];                             \
    float4 vra0=v4_[lane],      vra1=v4_[64+lane],                            \
           vrb0=v4_[128+lane],  vrb1=v4_[192+lane];                           \
    float4 ca0=make_float4(0,0,0,0), ca1=ca0, cb0=ca0, cb1=ca0;               \
    _Pragma("unroll")                                                         \
    for (int i_ = 0; i_ < RREG; ++i_)                                         \
        DOROW(QA[i_], QB[i_], wave*8+i_, AB);                                 \
    _Pragma("unroll")                                                         \
    for (int j_ = 0; j_ < RLDS; ++j_) {                                       \
        uint4 la_ = Glds[AB][wave*RLDS+j_][lane];                             \
        uint4 lb_ = Glds[AB][wave*RLDS+j_][64+lane];                          \
        DOROW(la_, lb_, wave*8+RREG+j_, AB);                                  \
    }                                                                         \
    if (wave >= 4) {                                                          \
        float4* p4_ = (float4*)part4[wave-4];                                 \
        p4_[lane]=ca0; p4_[64+lane]=ca1; p4_[128+lane]=cb0; p4_[192+lane]=cb1;\
    }                                                                         \
    __syncthreads();                                                          \
    if (wave < 4) {                                                           \
        float4* p4_ = (float4*)part4[wave];                                   \
        float4 x0_=p4_[lane], x1_=p4_[64+lane],                               \
               x2_=p4_[128+lane], x3_=p4_[192+lane];                          \
        ADD4_(ca0,x0_); ADD4_(ca1,x1_); ADD4_(cb0,x2_); ADD4_(cb1,x3_);       \
        p4_[lane]=ca0; p4_[64+lane]=ca1; p4_[128+lane]=cb0; p4_[192+lane]=cb1;\
    }                                                                         \
    __syncthreads();                                                          \
    {                                                                         \
        const float2* q0_=(const float2*)part4[0];                            \
        const float2* q1_=(const float2*)part4[1];                            \
        const float2* q2_=(const float2*)part4[2];                            \
        const float2* q3_=(const float2*)part4[3];                            \
        float2 s_=q0_[tid], t1_=q1_[tid], t2_=q2_[tid], t3_=q3_[tid];         \
        s_.x = (s_.x + t1_.x) + (t2_.x + t3_.x);                              \
        s_.y = (s_.y + t1_.y) + (t2_.y + t3_.y);                              \
        float2* pg_ = (float2*)(partials +                                    \
            (((size_t)(PAR)*BS + (BATCH))*WPB + k)*M);                        \
        pg_[tid] = s_;                                                        \
    }                                                                         \
    __syncthreads();                                                          \
    if (tid == 0)                                                             \
        __hip_atomic_fetch_add(cnt + (BATCH)*32, 1u, __ATOMIC_RELEASE,        \
                               __HIP_MEMORY_SCOPE_AGENT);                     \
} while (0)

// v = NU / sum of 16 WG partials (fixed order -> bitwise-identical in all
// 16 WGs of the batch -> uniform local convergence decision).
#define VRED(AB, BATCH, PAR, VOLD) do {                                       \
    const float2* pa_ = (const float2*)(partials +                            \
        (((size_t)(PAR)*BS + (BATCH))*WPB)*M);                                \
    float2 s_ = pa_[tid];                                                     \
    _Pragma("unroll")                                                         \
    for (int p_ = 1; p_ < WPB; ++p_) {                                        \
        float2 q_ = pa_[(size_t)p_*(M/2) + tid];                              \
        s_.x += q_.x; s_.y += q_.y;                                           \
    }                                                                         \
    float2 vn_ = make_float2(NU / s_.x, NU / s_.y);                           \
    if ((__float_as_uint(vn_.x) != __float_as_uint(VOLD.x)) ||                \
        (__float_as_uint(vn_.y) != __float_as_uint(VOLD.y))) same[AB] = 0;    \
    VOLD = vn_;                                                               \
    ((float2*)v_lds[AB])[tid] = vn_;                                          \
} while (0)

#define EMITROW(QAV, QBV, OFF, UN) do {                                       \
    float2 g0_=upair((QAV).x), g1_=upair((QAV).y),                            \
           g2_=upair((QAV).z), g3_=upair((QAV).w);                            \
    float2 h0_=upair((QBV).x), h1_=upair((QBV).y),                            \
           h2_=upair((QBV).z), h3_=upair((QBV).w);                            \
    float4* o4_ = (float4*)(Gout + (OFF));                                    \
    o4_[lane]      = make_float4((UN)*g0_.x*vra0.x, (UN)*g0_.y*vra0.y,        \
                                 (UN)*g1_.x*vra0.z, (UN)*g1_.y*vra0.w);       \
    o4_[64+lane]   = make_float4((UN)*g2_.x*vra1.x, (UN)*g2_.y*vra1.y,        \
                                 (UN)*g3_.x*vra1.z, (UN)*g3_.y*vra1.w);       \
    o4_[128+lane]  = make_float4((UN)*h0_.x*vrb0.x, (UN)*h0_.y*vrb0.y,        \
                                 (UN)*h1_.x*vrb0.z, (UN)*h1_.y*vrb0.w);       \
    o4_[192+lane]  = make_float4((UN)*h2_.x*vrb1.x, (UN)*h2_.y*vrb1.y,        \
                                 (UN)*h3_.x*vrb1.z, (UN)*h3_.y*vrb1.w);       \
} while (0)

#define EMIT(AB, SL, QA, QB) do {                                             \
    const float4* v4_ = (const float4*)v_lds[AB];                             \
    float4 vra0=v4_[lane],      vra1=v4_[64+lane],                            \
           vrb0=v4_[128+lane],  vrb1=v4_[192+lane];                           \
    _Pragma("unroll")                                                         \
    for (int i_ = 0; i_ < RREG; ++i_) {                                       \
        float un_ = u_lds[AB][wave*8+i_] * nN;                                \
        EMITROW(QA[i_], QB[i_], (SL) + (size_t)(wave*8+i_)*M, un_);           \
    }                                                                         \
    _Pragma("unroll")                                                         \
    for (int j_ = 0; j_ < RLDS; ++j_) {                                       \
        float un_ = u_lds[AB][wave*8+RREG+j_] * nN;                           \
        uint4 la_ = Glds[AB][wave*RLDS+j_][lane];                             \
        uint4 lb_ = Glds[AB][wave*RLDS+j_][64+lane];                          \
        EMITROW(la_, lb_, (SL) + (size_t)(wave*8+RREG+j_)*M, un_);            \
    }                                                                         \
} while (0)

__global__ __launch_bounds__(T, 2) void sinkhorn_pipe(
    const float* __restrict__ C,
    float* __restrict__ Gout,            // d_out: final Gamma*n only
    unsigned* __restrict__ cnt,          // [BS] stride-32 uints
    float* __restrict__ partials)        // [2][BS][WPB][M]
{
    const int bid  = blockIdx.x;
    const int p    = bid & 15;           // batch pair 0..15
    const int k    = bid >> 4;           // slice 0..15; bid%8==p%8 -> pair's
    const int tid  = threadIdx.x;        // 16 WGs co-located on one XCD
    const int lane = tid & 63;
    const int wave = tid >> 6;
    const int bA   = 2*p, bB = 2*p + 1;

    const size_t slA = ((size_t)bA * N + (size_t)k * RPB) * M;
    const size_t slB = ((size_t)bB * N + (size_t)k * RPB) * M;
    const float MU = 1.0f / (float)N;
    const float NU = 1.0f / (float)M;

    // LDS: 128K (G) + 16K (combine tree) + 8K (v) + 0.5K (u) ~= 152.5 KB
    __shared__ uint4 Glds[2][NW * RLDS][M / 8];
    __shared__ float part4[4][M];
    __shared__ float v_lds[2][M];
    __shared__ float u_lds[2][RPB];
    __shared__ int   same[2];

    // register payload: 2 batches x 4 rows x 2 uint4 per lane = 64 VGPR
    uint4 qA0[RREG], qB0[RREG], qA1[RREG], qB1[RREG];

    QUANT(slA, qA0, qB0, 0);
    QUANT(slB, qA1, qB1, 1);
    ((float2*)v_lds[0])[tid] = make_float2(NU, NU);
    ((float2*)v_lds[1])[tid] = make_float2(NU, NU);
    float2 voldA = make_float2(NU, NU), voldB = make_float2(NU, NU);
    __syncthreads();

    unsigned itA = 0, itB = 0;
    bool doneA = false, doneB = false;

    for (int t = 0; t < ITERS && !(doneA && doneB); ++t) {
        if (tid == 0) { same[0] = 1; same[1] = 1; }
        // ---- produce phase (arrive-early): A then B ----
        if (!doneA) { SWEEPCOMB(qA0, qB0, 0, bA, (int)(itA & 1)); itA++; }
        if (!doneB) { SWEEPCOMB(qA1, qB1, 1, bB, (int)(itB & 1)); itB++; }
        // ---- wait phase: both barriers should already be complete ----
        if (tid == 0) {
            if (!doneA) {
                const unsigned tgt = 16u * itA;
                while (__hip_atomic_load(cnt + bA*32, __ATOMIC_ACQUIRE,
                                         __HIP_MEMORY_SCOPE_AGENT) < tgt)
                    __builtin_amdgcn_s_sleep(1);
            }
            if (!doneB) {
                const unsigned tgt = 16u * itB;
                while (__hip_atomic_load(cnt + bB*32, __ATOMIC_ACQUIRE,
                                         __HIP_MEMORY_SCOPE_AGENT) < tgt)
                    __builtin_amdgcn_s_sleep(1);
            }
        }
        __syncthreads();
        // ---- consume phase: both batches' partial reads issue back-to-back
        if (!doneA) VRED(0, bA, (int)((itA - 1) & 1), voldA);
        if (!doneB) VRED(1, bB, (int)((itB - 1) & 1), voldB);
        __syncthreads();
        if (!doneA) doneA = (same[0] != 0);   // bitwise fixed point: all
        if (!doneB) doneB = (same[1] != 0);   // later iterations identical
        __syncthreads();
    }

    // ---- epilogue: Gamma*n = u' * Ghat * v * N for both batches ----
    const float nN = (float)N;
    EMIT(0, slA, qA0, qB0);
    EMIT(1, slB, qA1, qB1);
}

extern "C" void kernel_launch(void* const* d_in, const int* in_sizes, int n_in,
                              void* d_out, int out_size, void* d_ws, size_t ws_size,
                              hipStream_t stream) {
    (void)in_sizes; (void)n_in; (void)out_size;

    const float* C = (const float*)d_in[0];
    float* Gout = (float*)d_out;
    char* ws = (char*)d_ws;

    if (ws_size < WS_NEEDED) return;   // fail loudly (output stays poisoned)

    // Re-zero barrier counters every launch (graph-replay safe).
    hipMemsetAsync(d_ws, 0, CNT_BYTES, stream);

    unsigned* cnt   = (unsigned*)ws;
    float* partials = (float*)(ws + PART_OFF);
    sinkhorn_pipe<<<dim3(BS * WPB / 2), dim3(T), 0, stream>>>(
        C, Gout, cnt, partials);
}